// Round 10
// baseline (325.848 us; speedup 1.0000x reference)
//
#include <hip/hip_runtime.h>
#include <math.h>

#define Bb 64
#define Dd 4096
#define Hh 32
#define Kk 128
#define Vv 128
#define Mm 4096
#define MC 4097
#define NCH 16           // flash m-chunks (256 m each)
#define NSLOT 17         // 16 chunks + new-token slot

// workspace layout (float offsets)
#define WS_K1P  0                              // k1 partials: 34*16*8192
#define WS_Q    4456448                        // 262144
#define WS_NEWK (WS_Q + Bb*Hh*Kk)
#define WS_NEWV (WS_NEWK + Bb*Kk)
#define WS_PM   (WS_NEWV + Bb*Vv)              // 64*17*32
#define WS_PL   (WS_PM + Bb*NSLOT*Hh)
#define WS_PO   (WS_PL + Bb*NSLOT*Hh)          // 64*17*32*128
#define WS_O    (WS_PO + Bb*NSLOT*Hh*Vv)       // 262144
#define WS_YP   (WS_O + Bb*Hh*Vv)              // 8*262144

#define YSLOT (Bb*Dd)

// d_out layout (float offsets): y, Kc, Vc
#define OUT_Y  0
#define OUT_KC (Bb*Dd)
#define OUT_VC (OUT_KC + Bb*MC*Kk)

// LDS-only barrier: does NOT drain vmcnt, so global stores stay in flight.
#define BAR_LGKM() do { \
    __builtin_amdgcn_sched_barrier(0); \
    asm volatile("s_waitcnt lgkmcnt(0)" ::: "memory"); \
    __builtin_amdgcn_s_barrier(); \
    __builtin_amdgcn_sched_barrier(0); \
} while (0)

// ---------------- K1A: partial projections over d-chunk of 256
__global__ __launch_bounds__(256) void k1A_proj(const float* __restrict__ x,
        const float* __restrict__ Pq, const float* __restrict__ Pk,
        const float* __restrict__ Pv, float* __restrict__ part) {
    const int hidx = blockIdx.x;
    const int d0c  = blockIdx.y * 256;
    const int t = threadIdx.x;
    const int kg = t & 15, bg = t >> 4;
    const int kd = kg * 4, b0 = bg * 4;

    const float* P;
    if (hidx < Hh)       P = Pq + (size_t)hidx * Dd * Kk;
    else if (hidx == Hh) P = Pk;
    else                 P = Pv;

    __shared__ float xs[32 * 65];
    __shared__ float ps[32 * 128];

    float acc[4][8];
    #pragma unroll
    for (int a = 0; a < 4; a++)
        #pragma unroll
        for (int c = 0; c < 8; c++) acc[a][c] = 0.f;

    for (int tt = 0; tt < 8; tt++) {
        const int d0 = d0c + tt * 32;
        #pragma unroll
        for (int ii = 0; ii < 8; ii++) {
            int f = ii * 256 + t;
            int i = f & 31, bb = f >> 5;
            xs[i * 65 + bb] = x[(size_t)bb * Dd + d0 + i];
        }
        #pragma unroll
        for (int ii = 0; ii < 4; ii++) {
            int f = ii * 256 + t;
            int i = f >> 5, k4 = (f & 31) * 4;
            *(float4*)&ps[i * 128 + k4] = *(const float4*)&P[(size_t)(d0 + i) * Kk + k4];
        }
        __syncthreads();
        #pragma unroll
        for (int i = 0; i < 32; i++) {
            float xb[4];
            #pragma unroll
            for (int a = 0; a < 4; a++) xb[a] = xs[i * 65 + b0 + a];
            float4 p0 = *(float4*)&ps[i * 128 + kd];
            float4 p1 = *(float4*)&ps[i * 128 + 64 + kd];
            float pp[8] = {p0.x, p0.y, p0.z, p0.w, p1.x, p1.y, p1.z, p1.w};
            #pragma unroll
            for (int a = 0; a < 4; a++)
                #pragma unroll
                for (int c = 0; c < 8; c++)
                    acc[a][c] = fmaf(xb[a], pp[c], acc[a][c]);
        }
        __syncthreads();
    }
    float* dst = part + ((size_t)hidx * 16 + blockIdx.y) * 8192;
    #pragma unroll
    for (int a = 0; a < 4; a++) {
        int b = b0 + a;
        *(float4*)&dst[b * 128 + kd]      = make_float4(acc[a][0], acc[a][1], acc[a][2], acc[a][3]);
        *(float4*)&dst[b * 128 + 64 + kd] = make_float4(acc[a][4], acc[a][5], acc[a][6], acc[a][7]);
    }
}

// ---------------- K1B: reduce 16 chunks -> q / new_k / new_v
__global__ __launch_bounds__(256) void k1B_reduce(const float* __restrict__ part,
        float* __restrict__ ws) {
    const int o = blockIdx.x * 256 + threadIdx.x;
    const int hidx = o >> 13;
    const int rest = o & 8191;
    float s = 0.f;
    #pragma unroll
    for (int c = 0; c < 16; c++) s += part[((size_t)hidx * 16 + c) * 8192 + rest];
    if (hidx < Hh) {
        int b = rest >> 7, k = rest & 127;
        ws[WS_Q + ((size_t)b * Hh + hidx) * Kk + k] = s;
    } else if (hidx == Hh) {
        ws[WS_NEWK + rest] = s;
    } else {
        ws[WS_NEWV + rest] = s;
    }
}

// ---------------- KFLASH v8: v2 math/tiling exactly; q in registers with
// per-half qs staging; V staged in m-halves; 50 KB LDS -> 3 blocks/CU;
// raw lgkm-only barriers (stores drain under compute). No prefetch.
// block 256 = (hg 0..15) x (lg 0..15); thread owns h = {2hg, 2hg+1}.
__global__ __launch_bounds__(256, 3) void kflash(const float* __restrict__ prevK,
        const float* __restrict__ prevV, const float* __restrict__ wq,
        float* __restrict__ outKc, float* __restrict__ outVc,
        float* __restrict__ PM, float* __restrict__ PL, float* __restrict__ PO) {
    const int c = blockIdx.x;      // 0..15
    const int b = blockIdx.y;
    const int t = threadIdx.x;
    const int hg = t >> 4, lg = t & 15;
    const int h2 = hg * 2;
    const int kq = t & 15;
    const int mK = t >> 4;
    const int vq = t & 31;
    const int mV = t >> 5;

    __shared__ float ks_t[64 * 64];   // [k_half][m], ring-swizzled   (16.0 KB)
    __shared__ float vs[32 * 132];    // [m_half][v], natural         (16.9 KB)
    __shared__ float qs[64 * 34];     // [k_half][h]                  ( 8.7 KB)
    __shared__ float wl_t[64 * 36];   // [m][h]                       ( 9.2 KB)

    // ---- q fragment in registers: this thread's h2,h2+1 rows, k = hf*64+lg*4..+3
    float4 qreg[2][2];
    #pragma unroll
    for (int hf = 0; hf < 2; hf++)
        #pragma unroll
        for (int a = 0; a < 2; a++)
            qreg[hf][a] = *(const float4*)&wq[((size_t)b * Hh + h2 + a) * Kk + hf * 64 + lg * 4];

    float rm[2] = {-3.0e38f, -3.0e38f};
    float rl[2] = {0.f, 0.f};
    float accO[2][8] = {};

    for (int st = 0; st < 4; st++) {
        const int m0 = c * 256 + st * 64;
        BAR_LGKM();                                       // S1: prior readers done
        // ---- global loads (blocking, v2 style)
        float4 ka[8], va[8];
        #pragma unroll
        for (int ii = 0; ii < 4; ii++) {
            int mm = mK + ii * 16;
            const float* src = prevK + ((size_t)b * Mm + m0 + mm) * Kk + kq * 4;
            ka[ii]     = *(const float4*)src;
            ka[ii + 4] = *(const float4*)(src + 64);
        }
        #pragma unroll
        for (int ii = 0; ii < 8; ii++) {
            int mm = mV + ii * 8;
            va[ii] = *(const float4*)(prevV + ((size_t)b * Mm + m0 + mm) * Vv + vq * 4);
        }
        // ---- stage: V half A (m 0..31), K half0 (k 0..63), qs half0
        #pragma unroll
        for (int ii = 0; ii < 4; ii++)
            *(float4*)&vs[(mV + ii * 8) * 132 + vq * 4] = va[ii];
        #pragma unroll
        for (int ii = 0; ii < 4; ii++) {
            int mm = mK + ii * 16;
            int cs = (mm + 4 * kq) & 63;
            ks_t[(kq*4+0)*64 + cs] = ka[ii].x;
            ks_t[(kq*4+1)*64 + cs] = ka[ii].y;
            ks_t[(kq*4+2)*64 + cs] = ka[ii].z;
            ks_t[(kq*4+3)*64 + cs] = ka[ii].w;
        }
        {
            float q0[4] = {qreg[0][0].x, qreg[0][0].y, qreg[0][0].z, qreg[0][0].w};
            float q1[4] = {qreg[0][1].x, qreg[0][1].y, qreg[0][1].z, qreg[0][1].w};
            #pragma unroll
            for (int j = 0; j < 4; j++)
                *(float2*)&qs[(lg * 4 + j) * 34 + h2] = make_float2(q0[j], q1[j]);
        }
        BAR_LGKM();                                       // S2: stage visible
        // ---- Kc/Vc write-through (drains across raw barriers)
        #pragma unroll
        for (int ii = 0; ii < 4; ii++) {
            int mm = mK + ii * 16;
            float* dK = outKc + ((size_t)b * MC + m0 + mm) * Kk + kq * 4;
            *(float4*)dK        = ka[ii];
            *(float4*)(dK + 64) = ka[ii + 4];
        }
        #pragma unroll
        for (int ii = 0; ii < 8; ii++) {
            int mm = mV + ii * 8;
            *(float4*)(outVc + ((size_t)b * MC + m0 + mm) * Vv + vq * 4) = va[ii];
        }
        // ---- QK half0: k = 0..63
        float s[2][4] = {{0.f,0.f,0.f,0.f},{0.f,0.f,0.f,0.f}};
        #pragma unroll 4
        for (int k = 0; k < 64; k++) {
            float2 q2 = *(float2*)&qs[k * 34 + h2];
            float4 k4 = *(float4*)&ks_t[k * 64 + ((4*lg + 4*(k>>2)) & 63)];
            s[0][0] = fmaf(q2.x, k4.x, s[0][0]); s[0][1] = fmaf(q2.x, k4.y, s[0][1]);
            s[0][2] = fmaf(q2.x, k4.z, s[0][2]); s[0][3] = fmaf(q2.x, k4.w, s[0][3]);
            s[1][0] = fmaf(q2.y, k4.x, s[1][0]); s[1][1] = fmaf(q2.y, k4.y, s[1][1]);
            s[1][2] = fmaf(q2.y, k4.z, s[1][2]); s[1][3] = fmaf(q2.y, k4.w, s[1][3]);
        }
        BAR_LGKM();                                       // S3: half0 reads done
        // ---- stage K half1 (k 64..127) + qs half1
        #pragma unroll
        for (int ii = 0; ii < 4; ii++) {
            int mm = mK + ii * 16;
            int cs = (mm + 4 * kq) & 63;
            ks_t[(kq*4+0)*64 + cs] = ka[ii+4].x;
            ks_t[(kq*4+1)*64 + cs] = ka[ii+4].y;
            ks_t[(kq*4+2)*64 + cs] = ka[ii+4].z;
            ks_t[(kq*4+3)*64 + cs] = ka[ii+4].w;
        }
        {
            float q0[4] = {qreg[1][0].x, qreg[1][0].y, qreg[1][0].z, qreg[1][0].w};
            float q1[4] = {qreg[1][1].x, qreg[1][1].y, qreg[1][1].z, qreg[1][1].w};
            #pragma unroll
            for (int j = 0; j < 4; j++)
                *(float2*)&qs[(lg * 4 + j) * 34 + h2] = make_float2(q0[j], q1[j]);
        }
        BAR_LGKM();                                       // S4: half1 visible
        // ---- QK half1
        #pragma unroll 4
        for (int k = 0; k < 64; k++) {
            float2 q2 = *(float2*)&qs[k * 34 + h2];
            float4 k4 = *(float4*)&ks_t[k * 64 + ((4*lg + 4*(k>>2)) & 63)];
            s[0][0] = fmaf(q2.x, k4.x, s[0][0]); s[0][1] = fmaf(q2.x, k4.y, s[0][1]);
            s[0][2] = fmaf(q2.x, k4.z, s[0][2]); s[0][3] = fmaf(q2.x, k4.w, s[0][3]);
            s[1][0] = fmaf(q2.y, k4.x, s[1][0]); s[1][1] = fmaf(q2.y, k4.y, s[1][1]);
            s[1][2] = fmaf(q2.y, k4.z, s[1][2]); s[1][3] = fmaf(q2.y, k4.w, s[1][3]);
        }
        // ---- register online softmax (reduce over lg lanes; same as v2)
        float al[2];
        #pragma unroll
        for (int a = 0; a < 2; a++) {
            float mloc = fmaxf(fmaxf(s[a][0], s[a][1]), fmaxf(s[a][2], s[a][3]));
            mloc = fmaxf(mloc, __shfl_xor(mloc, 1, 64));
            mloc = fmaxf(mloc, __shfl_xor(mloc, 2, 64));
            mloc = fmaxf(mloc, __shfl_xor(mloc, 4, 64));
            mloc = fmaxf(mloc, __shfl_xor(mloc, 8, 64));
            float nm = fmaxf(rm[a], mloc);
            al[a] = __expf(rm[a] - nm);
            float psum = 0.f;
            #pragma unroll
            for (int cc = 0; cc < 4; cc++) {
                float p = __expf(s[a][cc] - nm);
                wl_t[(4*lg + cc) * 36 + h2 + a] = p;      // same-wave columns
                psum += p;
            }
            psum += __shfl_xor(psum, 1, 64);
            psum += __shfl_xor(psum, 2, 64);
            psum += __shfl_xor(psum, 4, 64);
            psum += __shfl_xor(psum, 8, 64);
            rl[a] = rl[a] * al[a] + psum;
            rm[a] = nm;
        }
        #pragma unroll
        for (int a = 0; a < 2; a++)
            #pragma unroll
            for (int j = 0; j < 8; j++) accO[a][j] *= al[a];
        // ---- PV phase A (m 0..31; wl_t same-wave RAW)
        #pragma unroll 4
        for (int mm = 0; mm < 32; mm++) {
            float2 w2 = *(float2*)&wl_t[mm * 36 + h2];
            float4 v0 = *(float4*)&vs[mm * 132 + 4 * lg];
            float4 v1 = *(float4*)&vs[mm * 132 + 64 + 4 * lg];
            accO[0][0] = fmaf(w2.x, v0.x, accO[0][0]);
            accO[0][1] = fmaf(w2.x, v0.y, accO[0][1]);
            accO[0][2] = fmaf(w2.x, v0.z, accO[0][2]);
            accO[0][3] = fmaf(w2.x, v0.w, accO[0][3]);
            accO[0][4] = fmaf(w2.x, v1.x, accO[0][4]);
            accO[0][5] = fmaf(w2.x, v1.y, accO[0][5]);
            accO[0][6] = fmaf(w2.x, v1.z, accO[0][6]);
            accO[0][7] = fmaf(w2.x, v1.w, accO[0][7]);
            accO[1][0] = fmaf(w2.y, v0.x, accO[1][0]);
            accO[1][1] = fmaf(w2.y, v0.y, accO[1][1]);
            accO[1][2] = fmaf(w2.y, v0.z, accO[1][2]);
            accO[1][3] = fmaf(w2.y, v0.w, accO[1][3]);
            accO[1][4] = fmaf(w2.y, v1.x, accO[1][4]);
            accO[1][5] = fmaf(w2.y, v1.y, accO[1][5]);
            accO[1][6] = fmaf(w2.y, v1.z, accO[1][6]);
            accO[1][7] = fmaf(w2.y, v1.w, accO[1][7]);
        }
        BAR_LGKM();                                       // S5: vsA reads done
        #pragma unroll
        for (int ii = 0; ii < 4; ii++)                    // stage V half B (m 32..63)
            *(float4*)&vs[(mV + ii * 8) * 132 + vq * 4] = va[ii + 4];
        BAR_LGKM();                                       // S6: vsB visible
        // ---- PV phase B (m 32..63)
        #pragma unroll 4
        for (int mm = 0; mm < 32; mm++) {
            float2 w2 = *(float2*)&wl_t[(32 + mm) * 36 + h2];
            float4 v0 = *(float4*)&vs[mm * 132 + 4 * lg];
            float4 v1 = *(float4*)&vs[mm * 132 + 64 + 4 * lg];
            accO[0][0] = fmaf(w2.x, v0.x, accO[0][0]);
            accO[0][1] = fmaf(w2.x, v0.y, accO[0][1]);
            accO[0][2] = fmaf(w2.x, v0.z, accO[0][2]);
            accO[0][3] = fmaf(w2.x, v0.w, accO[0][3]);
            accO[0][4] = fmaf(w2.x, v1.x, accO[0][4]);
            accO[0][5] = fmaf(w2.x, v1.y, accO[0][5]);
            accO[0][6] = fmaf(w2.x, v1.z, accO[0][6]);
            accO[0][7] = fmaf(w2.x, v1.w, accO[0][7]);
            accO[1][0] = fmaf(w2.y, v0.x, accO[1][0]);
            accO[1][1] = fmaf(w2.y, v0.y, accO[1][1]);
            accO[1][2] = fmaf(w2.y, v0.z, accO[1][2]);
            accO[1][3] = fmaf(w2.y, v0.w, accO[1][3]);
            accO[1][4] = fmaf(w2.y, v1.x, accO[1][4]);
            accO[1][5] = fmaf(w2.y, v1.y, accO[1][5]);
            accO[1][6] = fmaf(w2.y, v1.z, accO[1][6]);
            accO[1][7] = fmaf(w2.y, v1.w, accO[1][7]);
        }
    }
    // write partials
    const size_t base = ((size_t)b * NSLOT + c) * Hh;
    if (lg == 0) {
        PM[base + h2]     = rm[0];
        PM[base + h2 + 1] = rm[1];
        PL[base + h2]     = rl[0];
        PL[base + h2 + 1] = rl[1];
    }
    #pragma unroll
    for (int a = 0; a < 2; a++) {
        float* po = PO + (base + h2 + a) * Vv;
        *(float4*)&po[4*lg]      = make_float4(accO[a][0], accO[a][1], accO[a][2], accO[a][3]);
        *(float4*)&po[64 + 4*lg] = make_float4(accO[a][4], accO[a][5], accO[a][6], accO[a][7]);
    }
}

// ---------------- KNEW: new-token slot NCH partial + Kc/Vc row 4096
__global__ __launch_bounds__(128) void knew(const float* __restrict__ ws,
        float* __restrict__ outKc, float* __restrict__ outVc,
        float* __restrict__ PM, float* __restrict__ PL, float* __restrict__ PO) {
    const int b = blockIdx.x, t = threadIdx.x;
    const float* q    = ws + WS_Q;
    const float* newk = ws + WS_NEWK;
    const float* newv = ws + WS_NEWV;
    const int h = t >> 2, j = t & 3;
    const float* qr = q + ((size_t)b * Hh + h) * Kk + j * 32;
    const float* nk = newk + (size_t)b * Kk + j * 32;
    float s0 = 0.f, s1 = 0.f, s2 = 0.f, s3 = 0.f;
    #pragma unroll
    for (int i = 0; i < 8; i++) {
        float4 a  = *(const float4*)&qr[i * 4];
        float4 c4 = *(const float4*)&nk[i * 4];
        s0 = fmaf(a.x, c4.x, s0); s1 = fmaf(a.y, c4.y, s1);
        s2 = fmaf(a.z, c4.z, s2); s3 = fmaf(a.w, c4.w, s3);
    }
    float s = (s0 + s1) + (s2 + s3);
    s += __shfl_xor(s, 1, 64);
    s += __shfl_xor(s, 2, 64);
    const size_t base = ((size_t)b * NSLOT + NCH) * Hh;
    if (j == 0) { PM[base + h] = s; PL[base + h] = 1.f; }
    float nv = newv[(size_t)b * Vv + t];
    outKc[((size_t)b * MC + Mm) * Kk + t] = newk[(size_t)b * Kk + t];
    outVc[((size_t)b * MC + Mm) * Vv + t] = nv;
    #pragma unroll 4
    for (int hh = 0; hh < Hh; hh++)
        PO[(base + hh) * Vv + t] = nv;
}

// ---------------- KCOMB: merge NSLOT partial slots -> O[b,h,v]
__global__ __launch_bounds__(128) void kcomb(const float* __restrict__ PM,
        const float* __restrict__ PL, const float* __restrict__ PO,
        float* __restrict__ O) {
    const int h = blockIdx.x, b = blockIdx.y, t = threadIdx.x;
    __shared__ float ml[NSLOT], ll[NSLOT];
    if (t < NSLOT) {
        ml[t] = PM[((size_t)b * NSLOT + t) * Hh + h];
        ll[t] = PL[((size_t)b * NSLOT + t) * Hh + h];
    }
    __syncthreads();
    float M = -3.0e38f;
    #pragma unroll
    for (int c = 0; c < NSLOT; c++) M = fmaxf(M, ml[c]);
    float L = 0.f, o = 0.f;
    #pragma unroll
    for (int c = 0; c < NSLOT; c++) {
        float e = __expf(ml[c] - M);
        L += ll[c] * e;
        o = fmaf(e, PO[(((size_t)b * NSLOT + c) * Hh + h) * Vv + t], o);
    }
    O[((size_t)b * Hh + h) * Vv + t] = o / L;
}

// ---------------- K5: y_part[hq][b,d] = sum_{h in quad, v} O[b,h,v] * P_o[h,d,v]
__global__ __launch_bounds__(256) void k5_outproj(const float* __restrict__ O,
        const float* __restrict__ Po, float* __restrict__ ypart) {
    const int dbase = blockIdx.x * 64;
    const int hq = blockIdx.y;
    const int t = threadIdx.x;
    __shared__ float os[64 * 64];   // [b][v-half], ring-swizzled
    __shared__ float ps2[64 * 64];  // [d][v-half], ring-swizzled
    const int dg = t & 15, bg = t >> 4;
    const int d0 = dg * 4, b0 = bg * 4;
    float acc[4][4] = {};
    for (int hi = 0; hi < 4; hi++) {
        const int h = hq * 4 + hi;
        for (int vh = 0; vh < 2; vh++) {
            __syncthreads();
            #pragma unroll
            for (int ii = 0; ii < 4; ii++) {
                int f = ii * 256 + t;
                int vq2 = f & 15, r = f >> 4;
                int colp = (4 * vq2 + 4 * (r >> 2)) & 63;
                *(float4*)&os[r * 64 + colp] =
                    *(const float4*)&O[((size_t)(r * Hh + h)) * Vv + vh * 64 + 4 * vq2];
                *(float4*)&ps2[r * 64 + colp] =
                    *(const float4*)&Po[((size_t)h * Dd + dbase + r) * Vv + vh * 64 + 4 * vq2];
            }
            __syncthreads();
            #pragma unroll
            for (int v4 = 0; v4 < 16; v4++) {
                float4 pd[4], ob[4];
                #pragma unroll
                for (int cc = 0; cc < 4; cc++)
                    pd[cc] = *(float4*)&ps2[(d0 + cc) * 64 + ((4*v4 + 4*dg) & 63)];
                #pragma unroll
                for (int a = 0; a < 4; a++)
                    ob[a] = *(float4*)&os[(b0 + a) * 64 + ((4*v4 + 4*bg) & 63)];
                #pragma unroll
                for (int a = 0; a < 4; a++)
                    #pragma unroll
                    for (int cc = 0; cc < 4; cc++) {
                        acc[a][cc] = fmaf(ob[a].x, pd[cc].x, acc[a][cc]);
                        acc[a][cc] = fmaf(ob[a].y, pd[cc].y, acc[a][cc]);
                        acc[a][cc] = fmaf(ob[a].z, pd[cc].z, acc[a][cc]);
                        acc[a][cc] = fmaf(ob[a].w, pd[cc].w, acc[a][cc]);
                    }
            }
        }
    }
    float* yp = ypart + (size_t)hq * YSLOT;
    #pragma unroll
    for (int a = 0; a < 4; a++)
        *(float4*)&yp[(size_t)(b0 + a) * Dd + dbase + d0] =
            make_float4(acc[a][0], acc[a][1], acc[a][2], acc[a][3]);
}

// ---------------- K5r: y = sum of 8 y-partial slots
__global__ __launch_bounds__(256) void k5r_yreduce(const float* __restrict__ ypart,
        float* __restrict__ y) {
    const int o = blockIdx.x * 256 + threadIdx.x;
    float s = 0.f;
    #pragma unroll
    for (int c = 0; c < 8; c++) s += ypart[(size_t)c * YSLOT + o];
    y[o] = s;
}

extern "C" void kernel_launch(void* const* d_in, const int* in_sizes, int n_in,
                              void* d_out, int out_size, void* d_ws, size_t ws_size,
                              hipStream_t stream) {
    const float* x     = (const float*)d_in[0];
    const float* prevK = (const float*)d_in[1];
    const float* prevV = (const float*)d_in[2];
    const float* Pq    = (const float*)d_in[3];
    const float* Pk    = (const float*)d_in[4];
    const float* Pv    = (const float*)d_in[5];
    const float* Po    = (const float*)d_in[6];
    float* out = (float*)d_out;
    float* ws  = (float*)d_ws;

    k1A_proj<<<dim3(Hh + 2, 16), 256, 0, stream>>>(x, Pq, Pk, Pv, ws + WS_K1P);
    k1B_reduce<<<(34 * 8192) / 256, 256, 0, stream>>>(ws + WS_K1P, ws);
    kflash<<<dim3(NCH, Bb), 256, 0, stream>>>(prevK, prevV, ws + WS_Q,
                                              out + OUT_KC, out + OUT_VC,
                                              ws + WS_PM, ws + WS_PL, ws + WS_PO);
    knew<<<Bb, 128, 0, stream>>>(ws, out + OUT_KC, out + OUT_VC,
                                 ws + WS_PM, ws + WS_PL, ws + WS_PO);
    kcomb<<<dim3(Hh, Bb), 128, 0, stream>>>(ws + WS_PM, ws + WS_PL, ws + WS_PO,
                                            ws + WS_O);
    k5_outproj<<<dim3(64, 8), 256, 0, stream>>>(ws + WS_O, Po, ws + WS_YP);
    k5r_yreduce<<<YSLOT / 256, 256, 0, stream>>>(ws + WS_YP, out + OUT_Y);
}

// Round 11
// 232.156 us; speedup vs baseline: 1.4036x; 1.4036x over previous
//
#include <hip/hip_runtime.h>
#include <math.h>

#define Bb 64
#define Dd 4096
#define Hh 32
#define Kk 128
#define Vv 128
#define Mm 4096
#define MC 4097
#define NCH 16           // flash m-chunks (256 m each)
#define NSLOT 17         // 16 chunks + new-token slot

// workspace layout (float offsets)
#define WS_K1P  0                              // k1 partials: 34*16*8192
#define WS_Q    4456448                        // 262144
#define WS_NEWK (WS_Q + Bb*Hh*Kk)
#define WS_NEWV (WS_NEWK + Bb*Kk)
#define WS_PM   (WS_NEWV + Bb*Vv)              // 64*17*32
#define WS_PL   (WS_PM + Bb*NSLOT*Hh)
#define WS_PO   (WS_PL + Bb*NSLOT*Hh)          // 64*17*32*128
#define WS_O    (WS_PO + Bb*NSLOT*Hh*Vv)       // 262144
#define WS_YP   (WS_O + Bb*Hh*Vv)              // 8*262144

#define YSLOT (Bb*Dd)

// d_out layout (float offsets): y, Kc, Vc
#define OUT_Y  0
#define OUT_KC (Bb*Dd)
#define OUT_VC (OUT_KC + Bb*MC*Kk)

// LDS-only barrier: waits LDS ops of this wave, then syncs. Does NOT drain
// vmcnt, so the Kc/Vc write-through stores stay in flight across it
// (__syncthreads would emit s_waitcnt vmcnt(0) and stall all waves).
#define BAR_LGKM() do { \
    __builtin_amdgcn_sched_barrier(0); \
    asm volatile("s_waitcnt lgkmcnt(0)" ::: "memory"); \
    __builtin_amdgcn_s_barrier(); \
    __builtin_amdgcn_sched_barrier(0); \
} while (0)

// ---------------- K1A: partial projections over d-chunk of 256
// grid (34, 16): x = proj index (0..31 heads, 32=P_k, 33=P_v), y = d-chunk
__global__ __launch_bounds__(256) void k1A_proj(const float* __restrict__ x,
        const float* __restrict__ Pq, const float* __restrict__ Pk,
        const float* __restrict__ Pv, float* __restrict__ part) {
    const int hidx = blockIdx.x;
    const int d0c  = blockIdx.y * 256;
    const int t = threadIdx.x;
    const int kg = t & 15, bg = t >> 4;
    const int kd = kg * 4, b0 = bg * 4;

    const float* P;
    if (hidx < Hh)       P = Pq + (size_t)hidx * Dd * Kk;
    else if (hidx == Hh) P = Pk;
    else                 P = Pv;

    __shared__ float xs[32 * 65];
    __shared__ float ps[32 * 128];

    float acc[4][8];
    #pragma unroll
    for (int a = 0; a < 4; a++)
        #pragma unroll
        for (int c = 0; c < 8; c++) acc[a][c] = 0.f;

    for (int tt = 0; tt < 8; tt++) {
        const int d0 = d0c + tt * 32;
        #pragma unroll
        for (int ii = 0; ii < 8; ii++) {
            int f = ii * 256 + t;
            int i = f & 31, bb = f >> 5;
            xs[i * 65 + bb] = x[(size_t)bb * Dd + d0 + i];
        }
        #pragma unroll
        for (int ii = 0; ii < 4; ii++) {
            int f = ii * 256 + t;
            int i = f >> 5, k4 = (f & 31) * 4;
            *(float4*)&ps[i * 128 + k4] = *(const float4*)&P[(size_t)(d0 + i) * Kk + k4];
        }
        __syncthreads();
        #pragma unroll
        for (int i = 0; i < 32; i++) {
            float xb[4];
            #pragma unroll
            for (int a = 0; a < 4; a++) xb[a] = xs[i * 65 + b0 + a];
            float4 p0 = *(float4*)&ps[i * 128 + kd];
            float4 p1 = *(float4*)&ps[i * 128 + 64 + kd];
            float pp[8] = {p0.x, p0.y, p0.z, p0.w, p1.x, p1.y, p1.z, p1.w};
            #pragma unroll
            for (int a = 0; a < 4; a++)
                #pragma unroll
                for (int c = 0; c < 8; c++)
                    acc[a][c] = fmaf(xb[a], pp[c], acc[a][c]);
        }
        __syncthreads();
    }
    float* dst = part + ((size_t)hidx * 16 + blockIdx.y) * 8192;
    #pragma unroll
    for (int a = 0; a < 4; a++) {
        int b = b0 + a;
        *(float4*)&dst[b * 128 + kd]      = make_float4(acc[a][0], acc[a][1], acc[a][2], acc[a][3]);
        *(float4*)&dst[b * 128 + 64 + kd] = make_float4(acc[a][4], acc[a][5], acc[a][6], acc[a][7]);
    }
}

// ---------------- K1B: reduce 16 chunks -> q / new_k / new_v
__global__ __launch_bounds__(256) void k1B_reduce(const float* __restrict__ part,
        float* __restrict__ ws) {
    const int o = blockIdx.x * 256 + threadIdx.x;
    const int hidx = o >> 13;
    const int rest = o & 8191;
    float s = 0.f;
    #pragma unroll
    for (int c = 0; c < 16; c++) s += part[((size_t)hidx * 16 + c) * 8192 + rest];
    if (hidx < Hh) {
        int b = rest >> 7, k = rest & 127;
        ws[WS_Q + ((size_t)b * Hh + hidx) * Kk + k] = s;
    } else if (hidx == Hh) {
        ws[WS_NEWK + rest] = s;
    } else {
        ws[WS_NEWV + rest] = s;
    }
}

// ---------------- KFLASH v9 = v2 (round-5, 172 us) with ONLY the barrier
// type changed: __syncthreads -> lgkm-only raw barrier. No prefetch, full-V
// LDS, q staged once per block. block 256 = (hg 0..15) x (lg 0..15).
__global__ __launch_bounds__(256) void kflash(const float* __restrict__ prevK,
        const float* __restrict__ prevV, const float* __restrict__ wq,
        float* __restrict__ outKc, float* __restrict__ outVc,
        float* __restrict__ PM, float* __restrict__ PL, float* __restrict__ PO) {
    const int c = blockIdx.x;      // 0..15
    const int b = blockIdx.y;
    const int t = threadIdx.x;
    const int hg = t >> 4, lg = t & 15;
    const int h2 = hg * 2;

    __shared__ float ks_t[64 * 64];   // [k_half][m], ring-swizzled
    __shared__ float vs[64 * 132];    // [m][v], natural
    __shared__ float qs[128 * 34];    // [k][h]
    __shared__ float wl_t[64 * 36];   // [m][h]

    // ---- stage q once (block-wide): 32h x 128k
    {
        const int h = t >> 3, kc = t & 7;
        const float* qr = wq + ((size_t)b * Hh + h) * Kk + kc * 16;
        float4 a0 = *(const float4*)&qr[0];
        float4 a1 = *(const float4*)&qr[4];
        float4 a2 = *(const float4*)&qr[8];
        float4 a3 = *(const float4*)&qr[12];
        const int k0 = kc * 16;
        qs[(k0+ 0)*34 + h] = a0.x; qs[(k0+ 1)*34 + h] = a0.y;
        qs[(k0+ 2)*34 + h] = a0.z; qs[(k0+ 3)*34 + h] = a0.w;
        qs[(k0+ 4)*34 + h] = a1.x; qs[(k0+ 5)*34 + h] = a1.y;
        qs[(k0+ 6)*34 + h] = a1.z; qs[(k0+ 7)*34 + h] = a1.w;
        qs[(k0+ 8)*34 + h] = a2.x; qs[(k0+ 9)*34 + h] = a2.y;
        qs[(k0+10)*34 + h] = a2.z; qs[(k0+11)*34 + h] = a2.w;
        qs[(k0+12)*34 + h] = a3.x; qs[(k0+13)*34 + h] = a3.y;
        qs[(k0+14)*34 + h] = a3.z; qs[(k0+15)*34 + h] = a3.w;
    }

    float rm[2] = {-3.0e38f, -3.0e38f};
    float rl[2] = {0.f, 0.f};
    float accO[2][8] = {};
    const int kq = t & 15;          // K-stage col chunk (4 floats)
    const int vq = t & 31;          // V-stage col chunk

    for (int st = 0; st < 4; st++) {
        const int m0 = c * 256 + st * 64;
        BAR_LGKM();                                       // S1: prior PV reads done
        float4 kreg[8], vreg[8];
        #pragma unroll
        for (int ii = 0; ii < 4; ii++) {
            int mm = (t >> 4) + ii * 16;
            const float* src = prevK + ((size_t)b * Mm + m0 + mm) * Kk + kq * 4;
            kreg[ii]     = *(const float4*)src;
            kreg[ii + 4] = *(const float4*)(src + 64);
        }
        #pragma unroll
        for (int ii = 0; ii < 8; ii++) {
            int mm = (t >> 5) + ii * 8;
            vreg[ii] = *(const float4*)(prevV + ((size_t)b * Mm + m0 + mm) * Vv + vq * 4);
        }
        // ds writes: K half 0 (transposed+swizzled), V natural
        #pragma unroll
        for (int ii = 0; ii < 4; ii++) {
            int mm = (t >> 4) + ii * 16;
            int cs = (mm + 4 * kq) & 63;
            ks_t[(kq*4+0)*64 + cs] = kreg[ii].x;
            ks_t[(kq*4+1)*64 + cs] = kreg[ii].y;
            ks_t[(kq*4+2)*64 + cs] = kreg[ii].z;
            ks_t[(kq*4+3)*64 + cs] = kreg[ii].w;
        }
        #pragma unroll
        for (int ii = 0; ii < 8; ii++) {
            int mm = (t >> 5) + ii * 8;
            *(float4*)&vs[mm * 132 + vq * 4] = vreg[ii];
        }
        BAR_LGKM();                                       // S2: stage visible
        // issue cache-copy stores (drain under QK across raw barriers)
        #pragma unroll
        for (int ii = 0; ii < 4; ii++) {
            int mm = (t >> 4) + ii * 16;
            float* dstK = outKc + ((size_t)b * MC + m0 + mm) * Kk + kq * 4;
            *(float4*)dstK        = kreg[ii];
            *(float4*)(dstK + 64) = kreg[ii + 4];
        }
        #pragma unroll
        for (int ii = 0; ii < 8; ii++) {
            int mm = (t >> 5) + ii * 8;
            *(float4*)(outVc + ((size_t)b * MC + m0 + mm) * Vv + vq * 4) = vreg[ii];
        }
        // QK-0: k = 0..63
        float s[2][4] = {};
        #pragma unroll 4
        for (int k = 0; k < 64; k++) {
            float2 q2 = *(float2*)&qs[k * 34 + h2];
            float4 k4 = *(float4*)&ks_t[k * 64 + ((4*lg + 4*(k>>2)) & 63)];
            s[0][0] = fmaf(q2.x, k4.x, s[0][0]); s[0][1] = fmaf(q2.x, k4.y, s[0][1]);
            s[0][2] = fmaf(q2.x, k4.z, s[0][2]); s[0][3] = fmaf(q2.x, k4.w, s[0][3]);
            s[1][0] = fmaf(q2.y, k4.x, s[1][0]); s[1][1] = fmaf(q2.y, k4.y, s[1][1]);
            s[1][2] = fmaf(q2.y, k4.z, s[1][2]); s[1][3] = fmaf(q2.y, k4.w, s[1][3]);
        }
        BAR_LGKM();                                       // S3: QK-0 reads done
        #pragma unroll
        for (int ii = 0; ii < 4; ii++) {                  // K half 1
            int mm = (t >> 4) + ii * 16;
            int cs = (mm + 4 * kq) & 63;
            ks_t[(kq*4+0)*64 + cs] = kreg[ii+4].x;
            ks_t[(kq*4+1)*64 + cs] = kreg[ii+4].y;
            ks_t[(kq*4+2)*64 + cs] = kreg[ii+4].z;
            ks_t[(kq*4+3)*64 + cs] = kreg[ii+4].w;
        }
        BAR_LGKM();                                       // S4: K half1 ready
        // QK-1: k = 64..127
        #pragma unroll 4
        for (int k = 0; k < 64; k++) {
            float2 q2 = *(float2*)&qs[(64 + k) * 34 + h2];
            float4 k4 = *(float4*)&ks_t[k * 64 + ((4*lg + 4*(k>>2)) & 63)];
            s[0][0] = fmaf(q2.x, k4.x, s[0][0]); s[0][1] = fmaf(q2.x, k4.y, s[0][1]);
            s[0][2] = fmaf(q2.x, k4.z, s[0][2]); s[0][3] = fmaf(q2.x, k4.w, s[0][3]);
            s[1][0] = fmaf(q2.y, k4.x, s[1][0]); s[1][1] = fmaf(q2.y, k4.y, s[1][1]);
            s[1][2] = fmaf(q2.y, k4.z, s[1][2]); s[1][3] = fmaf(q2.y, k4.w, s[1][3]);
        }
        // online softmax (per-thread registers; redundant across lg lanes)
        float al[2];
        #pragma unroll
        for (int a = 0; a < 2; a++) {
            float mloc = fmaxf(fmaxf(s[a][0], s[a][1]), fmaxf(s[a][2], s[a][3]));
            mloc = fmaxf(mloc, __shfl_xor(mloc, 1, 64));
            mloc = fmaxf(mloc, __shfl_xor(mloc, 2, 64));
            mloc = fmaxf(mloc, __shfl_xor(mloc, 4, 64));
            mloc = fmaxf(mloc, __shfl_xor(mloc, 8, 64));
            float nm = fmaxf(rm[a], mloc);
            al[a] = __expf(rm[a] - nm);
            float psum = 0.f;
            #pragma unroll
            for (int cc = 0; cc < 4; cc++) {
                float p = __expf(s[a][cc] - nm);
                wl_t[(4*lg + cc) * 36 + h2 + a] = p;
                psum += p;
            }
            psum += __shfl_xor(psum, 1, 64);
            psum += __shfl_xor(psum, 2, 64);
            psum += __shfl_xor(psum, 4, 64);
            psum += __shfl_xor(psum, 8, 64);
            rl[a] = rl[a] * al[a] + psum;
            rm[a] = nm;
        }
        #pragma unroll
        for (int a = 0; a < 2; a++)
            #pragma unroll
            for (int j = 0; j < 8; j++) accO[a][j] *= al[a];
        // PV (wl_t written/read by same wave; compiler orders via lgkmcnt)
        for (int mm = 0; mm < 64; mm++) {
            float2 w2 = *(float2*)&wl_t[mm * 36 + h2];
            float4 v0 = *(float4*)&vs[mm * 132 + 4 * lg];
            float4 v1 = *(float4*)&vs[mm * 132 + 64 + 4 * lg];
            accO[0][0] = fmaf(w2.x, v0.x, accO[0][0]);
            accO[0][1] = fmaf(w2.x, v0.y, accO[0][1]);
            accO[0][2] = fmaf(w2.x, v0.z, accO[0][2]);
            accO[0][3] = fmaf(w2.x, v0.w, accO[0][3]);
            accO[0][4] = fmaf(w2.x, v1.x, accO[0][4]);
            accO[0][5] = fmaf(w2.x, v1.y, accO[0][5]);
            accO[0][6] = fmaf(w2.x, v1.z, accO[0][6]);
            accO[0][7] = fmaf(w2.x, v1.w, accO[0][7]);
            accO[1][0] = fmaf(w2.y, v0.x, accO[1][0]);
            accO[1][1] = fmaf(w2.y, v0.y, accO[1][1]);
            accO[1][2] = fmaf(w2.y, v0.z, accO[1][2]);
            accO[1][3] = fmaf(w2.y, v0.w, accO[1][3]);
            accO[1][4] = fmaf(w2.y, v1.x, accO[1][4]);
            accO[1][5] = fmaf(w2.y, v1.y, accO[1][5]);
            accO[1][6] = fmaf(w2.y, v1.z, accO[1][6]);
            accO[1][7] = fmaf(w2.y, v1.w, accO[1][7]);
        }
    }
    // write partials
    const size_t base = ((size_t)b * NSLOT + c) * Hh;
    if (lg == 0) {
        PM[base + h2]     = rm[0];
        PM[base + h2 + 1] = rm[1];
        PL[base + h2]     = rl[0];
        PL[base + h2 + 1] = rl[1];
    }
    #pragma unroll
    for (int a = 0; a < 2; a++) {
        float* po = PO + (base + h2 + a) * Vv;
        *(float4*)&po[4*lg]      = make_float4(accO[a][0], accO[a][1], accO[a][2], accO[a][3]);
        *(float4*)&po[64 + 4*lg] = make_float4(accO[a][4], accO[a][5], accO[a][6], accO[a][7]);
    }
}

// ---------------- KNEW: new-token slot NCH partial + Kc/Vc row 4096
// grid 64 b, block 128 (32 h x 4 lanes)
__global__ __launch_bounds__(128) void knew(const float* __restrict__ ws,
        float* __restrict__ outKc, float* __restrict__ outVc,
        float* __restrict__ PM, float* __restrict__ PL, float* __restrict__ PO) {
    const int b = blockIdx.x, t = threadIdx.x;
    const float* q    = ws + WS_Q;
    const float* newk = ws + WS_NEWK;
    const float* newv = ws + WS_NEWV;
    const int h = t >> 2, j = t & 3;
    const float* qr = q + ((size_t)b * Hh + h) * Kk + j * 32;
    const float* nk = newk + (size_t)b * Kk + j * 32;
    float s0 = 0.f, s1 = 0.f, s2 = 0.f, s3 = 0.f;
    #pragma unroll
    for (int i = 0; i < 8; i++) {
        float4 a  = *(const float4*)&qr[i * 4];
        float4 c4 = *(const float4*)&nk[i * 4];
        s0 = fmaf(a.x, c4.x, s0); s1 = fmaf(a.y, c4.y, s1);
        s2 = fmaf(a.z, c4.z, s2); s3 = fmaf(a.w, c4.w, s3);
    }
    float s = (s0 + s1) + (s2 + s3);
    s += __shfl_xor(s, 1, 64);
    s += __shfl_xor(s, 2, 64);
    const size_t base = ((size_t)b * NSLOT + NCH) * Hh;
    if (j == 0) { PM[base + h] = s; PL[base + h] = 1.f; }
    float nv = newv[(size_t)b * Vv + t];
    outKc[((size_t)b * MC + Mm) * Kk + t] = newk[(size_t)b * Kk + t];
    outVc[((size_t)b * MC + Mm) * Vv + t] = nv;
    #pragma unroll 4
    for (int hh = 0; hh < Hh; hh++)
        PO[(base + hh) * Vv + t] = nv;
}

// ---------------- KCOMB: merge NSLOT partial slots -> O[b,h,v]
// grid (32 h, 64 b), block 128 (v)
__global__ __launch_bounds__(128) void kcomb(const float* __restrict__ PM,
        const float* __restrict__ PL, const float* __restrict__ PO,
        float* __restrict__ O) {
    const int h = blockIdx.x, b = blockIdx.y, t = threadIdx.x;
    __shared__ float ml[NSLOT], ll[NSLOT];
    if (t < NSLOT) {
        ml[t] = PM[((size_t)b * NSLOT + t) * Hh + h];
        ll[t] = PL[((size_t)b * NSLOT + t) * Hh + h];
    }
    __syncthreads();
    float M = -3.0e38f;
    #pragma unroll
    for (int c = 0; c < NSLOT; c++) M = fmaxf(M, ml[c]);
    float L = 0.f, o = 0.f;
    #pragma unroll
    for (int c = 0; c < NSLOT; c++) {
        float e = __expf(ml[c] - M);
        L += ll[c] * e;
        o = fmaf(e, PO[(((size_t)b * NSLOT + c) * Hh + h) * Vv + t], o);
    }
    O[((size_t)b * Hh + h) * Vv + t] = o / L;
}

// ---------------- K5: y_part[hq][b,d] = sum_{h in quad, v} O[b,h,v] * P_o[h,d,v]
// grid (64 d-tiles of 64, 8 h-quads of 4); ring-swizzled LDS (stride 64)
__global__ __launch_bounds__(256) void k5_outproj(const float* __restrict__ O,
        const float* __restrict__ Po, float* __restrict__ ypart) {
    const int dbase = blockIdx.x * 64;
    const int hq = blockIdx.y;
    const int t = threadIdx.x;
    __shared__ float os[64 * 64];   // [b][v-half], ring-swizzled
    __shared__ float ps2[64 * 64];  // [d][v-half], ring-swizzled
    const int dg = t & 15, bg = t >> 4;
    const int d0 = dg * 4, b0 = bg * 4;
    float acc[4][4] = {};   // [b][d]
    for (int hi = 0; hi < 4; hi++) {
        const int h = hq * 4 + hi;
        for (int vh = 0; vh < 2; vh++) {
            __syncthreads();
            #pragma unroll
            for (int ii = 0; ii < 4; ii++) {
                int f = ii * 256 + t;
                int vq2 = f & 15, r = f >> 4;
                int colp = (4 * vq2 + 4 * (r >> 2)) & 63;
                *(float4*)&os[r * 64 + colp] =
                    *(const float4*)&O[((size_t)(r * Hh + h)) * Vv + vh * 64 + 4 * vq2];
                *(float4*)&ps2[r * 64 + colp] =
                    *(const float4*)&Po[((size_t)h * Dd + dbase + r) * Vv + vh * 64 + 4 * vq2];
            }
            __syncthreads();
            #pragma unroll
            for (int v4 = 0; v4 < 16; v4++) {
                float4 pd[4], ob[4];
                #pragma unroll
                for (int cc = 0; cc < 4; cc++)
                    pd[cc] = *(float4*)&ps2[(d0 + cc) * 64 + ((4*v4 + 4*dg) & 63)];
                #pragma unroll
                for (int a = 0; a < 4; a++)
                    ob[a] = *(float4*)&os[(b0 + a) * 64 + ((4*v4 + 4*bg) & 63)];
                #pragma unroll
                for (int a = 0; a < 4; a++)
                    #pragma unroll
                    for (int cc = 0; cc < 4; cc++) {
                        acc[a][cc] = fmaf(ob[a].x, pd[cc].x, acc[a][cc]);
                        acc[a][cc] = fmaf(ob[a].y, pd[cc].y, acc[a][cc]);
                        acc[a][cc] = fmaf(ob[a].z, pd[cc].z, acc[a][cc]);
                        acc[a][cc] = fmaf(ob[a].w, pd[cc].w, acc[a][cc]);
                    }
            }
        }
    }
    float* yp = ypart + (size_t)hq * YSLOT;
    #pragma unroll
    for (int a = 0; a < 4; a++)
        *(float4*)&yp[(size_t)(b0 + a) * Dd + dbase + d0] =
            make_float4(acc[a][0], acc[a][1], acc[a][2], acc[a][3]);
}

// ---------------- K5r: y = sum of 8 y-partial slots
__global__ __launch_bounds__(256) void k5r_yreduce(const float* __restrict__ ypart,
        float* __restrict__ y) {
    const int o = blockIdx.x * 256 + threadIdx.x;
    float s = 0.f;
    #pragma unroll
    for (int c = 0; c < 8; c++) s += ypart[(size_t)c * YSLOT + o];
    y[o] = s;
}

extern "C" void kernel_launch(void* const* d_in, const int* in_sizes, int n_in,
                              void* d_out, int out_size, void* d_ws, size_t ws_size,
                              hipStream_t stream) {
    const float* x     = (const float*)d_in[0];
    const float* prevK = (const float*)d_in[1];
    const float* prevV = (const float*)d_in[2];
    const float* Pq    = (const float*)d_in[3];
    const float* Pk    = (const float*)d_in[4];
    const float* Pv    = (const float*)d_in[5];
    const float* Po    = (const float*)d_in[6];
    float* out = (float*)d_out;
    float* ws  = (float*)d_ws;

    k1A_proj<<<dim3(Hh + 2, 16), 256, 0, stream>>>(x, Pq, Pk, Pv, ws + WS_K1P);
    k1B_reduce<<<(34 * 8192) / 256, 256, 0, stream>>>(ws + WS_K1P, ws);
    kflash<<<dim3(NCH, Bb), 256, 0, stream>>>(prevK, prevV, ws + WS_Q,
                                              out + OUT_KC, out + OUT_VC,
                                              ws + WS_PM, ws + WS_PL, ws + WS_PO);
    knew<<<Bb, 128, 0, stream>>>(ws, out + OUT_KC, out + OUT_VC,
                                 ws + WS_PM, ws + WS_PL, ws + WS_PO);
    kcomb<<<dim3(Hh, Bb), 128, 0, stream>>>(ws + WS_PM, ws + WS_PL, ws + WS_PO,
                                            ws + WS_O);
    k5_outproj<<<dim3(64, 8), 256, 0, stream>>>(ws + WS_O, Po, ws + WS_YP);
    k5r_yreduce<<<YSLOT / 256, 256, 0, stream>>>(ws + WS_YP, out + OUT_Y);
}